// Round 35
// baseline (112.125 us; speedup 1.0000x reference)
//
#include <hip/hip_runtime.h>
#include <hip/hip_bf16.h>
#include <stdint.h>

// ---------------------------------------------------------------------------
// OptimizedMultiHeadAttn: x:[2,2048,1024] f32, attn_w:[3072,1024], attn_b:[3072],
// proj_w:[1024,1024], proj_b:[1024]  ->  out:[2,2048,1024] f32
// Pipeline: cvt3 -> QKV gemm_bt (scatter Q/K/V^T) -> flash attn -> proj gemm64
//
// FINAL (verified 111.79-112.42us over seven runs): cvt3 (near HBM roofline)
// -> gemm_qkv 128^2 (256,3), XCD-compact map, coalesced epilogues -> attn
// (46.9us: swapped QK/PV, exp2 softmax, defer-max, LDS-staged K/V dbuf,
// split-block paired causal schedule, 16 waves/CU) -> gemm_proj64 64x128,
// 512 blocks = 2/CU. Session: 304.7us baseline -> 111.8us, 2.73x.
// ---------------------------------------------------------------------------

typedef __bf16 bf16_t;
typedef __bf16 bf16x8 __attribute__((ext_vector_type(8)));
typedef float f32x4 __attribute__((ext_vector_type(4)));

#define B_SZ 2
#define S_LEN 2048
#define D_MODEL 1024
#define N_HEADS 16
#define D_HEAD 64
#define M_ROWS (B_SZ * S_LEN)          // 4096
#define QKV_N (3 * N_HEADS * D_HEAD)   // 3072

// Q pre-scale: 1/sqrt(64) * log2(e)  (softmax runs in exp2 domain)
#define Q_SCALE 0.1803368801111204f

// workspace layout (bytes); total 48 MiB
#define OFF_XB  (0ull)
#define OFF_WB  (8ull  << 20)
#define OFF_PWB (14ull << 20)
#define OFF_Q   (16ull << 20)
#define OFF_K   (24ull << 20)
#define OFF_VT  (32ull << 20)
#define OFF_AO  (40ull << 20)

__device__ __forceinline__ unsigned short f2bf_u(float f) {
  union { float f; unsigned u; } v; v.f = f;
  unsigned r = v.u + 0x7fffu + ((v.u >> 16) & 1u);  // RNE
  return (unsigned short)(r >> 16);
}
__device__ __forceinline__ bf16_t f2bf(float f) {
  unsigned short u = f2bf_u(f);
  return __builtin_bit_cast(bf16_t, u);
}
// v_cvt_pk_bf16_f32: D[15:0]=bf16(lo), D[31:16]=bf16(hi) (RNE). No builtin.
__device__ __forceinline__ unsigned cvt_pk_bf16(float lo, float hi) {
  unsigned r;
  asm volatile("v_cvt_pk_bf16_f32 %0, %1, %2" : "=v"(r) : "v"(lo), "v"(hi));
  return r;
}

// ---------------------------------------------------------------------------
__global__ void cvt3_f32_bf16(const float* __restrict__ sa, bf16_t* __restrict__ da, int n4a,
                              const float* __restrict__ sb, bf16_t* __restrict__ db, int n4b,
                              const float* __restrict__ sc, bf16_t* __restrict__ dc, int n4c) {
  int i = blockIdx.x * blockDim.x + threadIdx.x;
  const float* s; bf16_t* d; int j = i;
  if (i < n4a) { s = sa; d = da; }
  else if ((j = i - n4a) < n4b) { s = sb; d = db; }
  else if ((j = i - n4a - n4b) < n4c) { s = sc; d = dc; }
  else return;
  float4 f = reinterpret_cast<const float4*>(s)[j];
  ushort4 o;
  o.x = f2bf_u(f.x); o.y = f2bf_u(f.y); o.z = f2bf_u(f.z); o.w = f2bf_u(f.w);
  reinterpret_cast<ushort4*>(d)[j] = o;
}

// ---------------------------------------------------------------------------
// gemm_qkv: C = A * Bt^T + bias, 128x128 tile, BK=64, 4 waves.
// Single-buffer 2-barrier K-loop (m97 structure), (256,3), XCD-compact remap.
// Coalesced epilogues (verified R23).
#define BM 128
#define BN 128
#define BK 64

__device__ __forceinline__ void gload_lds16(const bf16_t* g, bf16_t* l) {
  __builtin_amdgcn_global_load_lds((__attribute__((address_space(1))) void*)g,
                                   (__attribute__((address_space(3))) void*)l,
                                   16, 0, 0);
}

__device__ __forceinline__ bf16x8 lds_frag(const bf16_t* lds, int row, int kchunk) {
  int pos = kchunk ^ (row & 7);
  return *reinterpret_cast<const bf16x8*>(lds + row * BK + pos * 8);
}

__global__ __launch_bounds__(256, 3) void gemm_qkv(
    const bf16_t* __restrict__ A, const bf16_t* __restrict__ Bt,
    const float* __restrict__ bias,
    bf16_t* __restrict__ qout, bf16_t* __restrict__ kout,
    bf16_t* __restrict__ vtout,
    int M, int N, int K) {
  // union LDS: K-loop uses As(16KB)+Bs(16KB); epilogue reuses as C-tile
  // (bf16 [128][136] = 34816B).
  __shared__ __align__(16) char smem[34816];
  bf16_t* As = reinterpret_cast<bf16_t*>(smem);
  bf16_t* Bs = As + BM * BK;

  const int tid = threadIdx.x;
  const int lane = tid & 63;
  const int wid = tid >> 6;
  const int wr = wid >> 1, wc = wid & 1;
  const int cl = lane & 15, hl = lane >> 4;

  // XCD-compact tile mapping (bijective): 768 blocks, 32m x 24n tiles
  const int id = blockIdx.x;
  const int xcd = id & 7, loc = id >> 3;
  const int mtile = (xcd & 3) * 8 + (loc & 7);
  const int ntile = (xcd >> 2) * 12 + (loc >> 3);
  const int m0 = mtile * BM, n0 = ntile * BN;

  f32x4 acc[4][4];
  #pragma unroll
  for (int m = 0; m < 4; ++m)
    #pragma unroll
    for (int n = 0; n < 4; ++n)
      acc[m][n] = (f32x4){0.f, 0.f, 0.f, 0.f};

  for (int kt = 0; kt < K; kt += BK) {
    #pragma unroll
    for (int it = 0; it < 4; ++it) {
      int chunk = it * 256 + tid;
      int row = chunk >> 3, cpos = chunk & 7;
      int csrc = cpos ^ (row & 7);
      bf16_t* ldsA = As + (it * 256 + wid * 64) * 8;
      bf16_t* ldsB = Bs + (it * 256 + wid * 64) * 8;
      gload_lds16(A  + (size_t)(m0 + row) * K + kt + csrc * 8, ldsA);
      gload_lds16(Bt + (size_t)(n0 + row) * K + kt + csrc * 8, ldsB);
    }
    __syncthreads();

    bf16x8 af[2][4], bfr[2][4];
    #pragma unroll
    for (int kk = 0; kk < 2; ++kk) {
      #pragma unroll
      for (int m = 0; m < 4; ++m)
        af[kk][m] = lds_frag(As, wr * 64 + m * 16 + cl, kk * 4 + hl);
      #pragma unroll
      for (int n = 0; n < 4; ++n)
        bfr[kk][n] = lds_frag(Bs, wc * 64 + n * 16 + cl, kk * 4 + hl);
    }
    __builtin_amdgcn_s_setprio(1);
    #pragma unroll
    for (int m = 0; m < 4; ++m)
      #pragma unroll
      for (int n = 0; n < 4; ++n) {
        acc[m][n] = __builtin_amdgcn_mfma_f32_16x16x32_bf16(af[0][m], bfr[0][n], acc[m][n], 0, 0, 0);
        acc[m][n] = __builtin_amdgcn_mfma_f32_16x16x32_bf16(af[1][m], bfr[1][n], acc[m][n], 0, 0, 0);
      }
    __builtin_amdgcn_s_setprio(0);
    __syncthreads();   // also guards LDS reuse by the epilogue below
  }

  // epilogue: C/D layout col=lane&15, row=(lane>>4)*4+j (m89-verified)
  const int part = n0 >> 10;         // 0=Q 1=K 2=V (tile never spans parts)
  const int b = m0 >> 11;
  const int sloc = m0 & 2047;        // batch-local s base
  if (part == 2) {
    // V^T: s contiguous in j -> pack and store 8B directly (no LDS)
    #pragma unroll
    for (int n = 0; n < 4; ++n) {
      int ng = n0 + wc * 64 + n * 16 + cl;
      float bv = bias[ng];
      int r = ng & 1023;
      int h = r >> 6, dk = r & 63;
      bf16_t* vrow = vtout + ((size_t)((b * N_HEADS + h) * D_HEAD + dk)) * S_LEN;
      #pragma unroll
      for (int m = 0; m < 4; ++m) {
        int sbase = sloc + wr * 64 + m * 16 + hl * 4;
        uint2 u;
        u.x = cvt_pk_bf16(acc[m][n][0] + bv, acc[m][n][1] + bv);
        u.y = cvt_pk_bf16(acc[m][n][2] + bv, acc[m][n][3] + bv);
        *reinterpret_cast<uint2*>(vrow + sbase) = u;
      }
    }
  } else {
    // Q/K: LDS transpose -> coalesced 128B row-segment stores
    const float scale = (part == 0) ? Q_SCALE : 1.0f;
    bf16_t (*ct)[136] = reinterpret_cast<bf16_t(*)[136]>(smem);
    #pragma unroll
    for (int n = 0; n < 4; ++n) {
      int colb = wc * 64 + n * 16 + cl;
      float bv = bias[n0 + colb];
      #pragma unroll
      for (int m = 0; m < 4; ++m)
        #pragma unroll
        for (int j = 0; j < 4; ++j) {
          int row = wr * 64 + m * 16 + hl * 4 + j;
          ct[row][colb] = f2bf((acc[m][n][j] + bv) * scale);
        }
    }
    __syncthreads();
    bf16_t* dst = (part == 0) ? qout : kout;
    const int row = tid >> 1, seg = tid & 1;
    const int ngs = n0 + seg * 64;
    const int h = (ngs & 1023) >> 6;
    const int s = sloc + row;          // batch-local
    bf16_t* drow = dst + ((size_t)((b * N_HEADS + h) * S_LEN + s)) * D_HEAD;
    #pragma unroll
    for (int kk = 0; kk < 8; ++kk) {   // 8 x 16B = full 64-elem dk segment
      uint4 v = *reinterpret_cast<const uint4*>(&ct[row][seg * 64 + kk * 8]);
      *reinterpret_cast<uint4*>(drow + kk * 8) = v;
    }
  }
}

// ---------------------------------------------------------------------------
// gemm_proj64: C[4096,1024] = A[4096,1024]*Bt[1024,1024]^T + bias (f32 out).
// 64x128 tile, BK=64, 4 waves (wave wid owns cols wid*32..+31: acc[4][2]).
// Grid 64m x 8n = 512 blocks = 2 blocks/CU (R30 occupancy fix). Same staging
// scheme; 2-pass f32 LDS-transpose epilogue. XCD-compact bijective map.
__global__ __launch_bounds__(256, 3) void gemm_proj64(
    const bf16_t* __restrict__ A, const bf16_t* __restrict__ Bt,
    const float* __restrict__ bias, float* __restrict__ fout,
    int M, int N, int K) {
  // LDS: K-loop As(8KB)+Bs(16KB)=24KB; epilogue f32 [64][68]=17408B.
  __shared__ __align__(16) char smem[34816];
  bf16_t* As = reinterpret_cast<bf16_t*>(smem);   // [64][64]
  bf16_t* Bs = As + 64 * 64;                      // [128][64]

  const int tid = threadIdx.x;
  const int lane = tid & 63;
  const int wid = tid >> 6;                       // 0..3 (column wave)
  const int cl = lane & 15, hl = lane >> 4;

  const int id = blockIdx.x;                      // 0..511
  const int xcd = id & 7, loc = id >> 3;          // loc 0..63
  const int mtile = xcd * 8 + (loc & 7);          // 0..63
  const int ntile = loc >> 3;                     // 0..7
  const int m0 = mtile * 64, n0 = ntile * 128;

  f32x4 acc[4][2];
  #pragma unroll
  for (int m = 0; m < 4; ++m)
    #pragma unroll
    for (int n = 0; n < 2; ++n)
      acc[m][n] = (f32x4){0.f, 0.f, 0.f, 0.f};

  for (int kt = 0; kt < K; kt += BK) {
    #pragma unroll
    for (int it = 0; it < 2; ++it) {
      int c = it * 256 + tid;
      int row = c >> 3, cpos = c & 7;
      int csrc = cpos ^ (row & 7);
      gload_lds16(A + (size_t)(m0 + row) * K + kt + csrc * 8,
                  As + (it * 256 + wid * 64) * 8);
    }
    #pragma unroll
    for (int it = 0; it < 4; ++it) {
      int c = it * 256 + tid;
      int row = c >> 3, cpos = c & 7;
      int csrc = cpos ^ (row & 7);
      gload_lds16(Bt + (size_t)(n0 + row) * K + kt + csrc * 8,
                  Bs + (it * 256 + wid * 64) * 8);
    }
    __syncthreads();

    bf16x8 af[2][4], bfr[2][2];
    #pragma unroll
    for (int kk = 0; kk < 2; ++kk) {
      #pragma unroll
      for (int m = 0; m < 4; ++m)
        af[kk][m] = lds_frag(As, m * 16 + cl, kk * 4 + hl);
      #pragma unroll
      for (int n = 0; n < 2; ++n)
        bfr[kk][n] = lds_frag(Bs, wid * 32 + n * 16 + cl, kk * 4 + hl);
    }
    __builtin_amdgcn_s_setprio(1);
    #pragma unroll
    for (int m = 0; m < 4; ++m)
      #pragma unroll
      for (int n = 0; n < 2; ++n) {
        acc[m][n] = __builtin_amdgcn_mfma_f32_16x16x32_bf16(af[0][m], bfr[0][n], acc[m][n], 0, 0, 0);
        acc[m][n] = __builtin_amdgcn_mfma_f32_16x16x32_bf16(af[1][m], bfr[1][n], acc[m][n], 0, 0, 0);
      }
    __builtin_amdgcn_s_setprio(0);
    __syncthreads();   // also guards LDS reuse by the epilogue below
  }

  // epilogue: f32 LDS transpose in two 64-col passes -> float4 stores.
  float (*ctf)[68] = reinterpret_cast<float(*)[68]>(smem);
  #pragma unroll 1
  for (int p = 0; p < 2; ++p) {
    if ((wid >> 1) == p) {
      const int colh = (wid & 1) * 32;
      #pragma unroll
      for (int n = 0; n < 2; ++n) {
        int coll = colh + n * 16 + cl;            // 0..63 within the pass
        float bv = bias[n0 + p * 64 + coll];
        #pragma unroll
        for (int m = 0; m < 4; ++m)
          #pragma unroll
          for (int j = 0; j < 4; ++j)
            ctf[m * 16 + hl * 4 + j][coll] = acc[m][n][j] + bv;
      }
    }
    __syncthreads();
    {
      const int row = tid >> 2, sub = tid & 3;    // 16 f32 (64B) per thread
      float* drow = fout + (size_t)(m0 + row) * N + n0 + p * 64 + sub * 16;
      #pragma unroll
      for (int kk = 0; kk < 4; ++kk) {
        float4 v = *reinterpret_cast<const float4*>(&ctf[row][sub * 16 + kk * 4]);
        *reinterpret_cast<float4*>(drow + kk * 4) = v;
      }
    }
    __syncthreads();
  }
}

// ---------------------------------------------------------------------------
// Flash attention (R18/R23 version — 46.9us measured).
// Causal, exp2 domain, swapped-operand, LDS-staged K/V; paired tiles split
// across two blocks: grid 512, half=blk>>8; CU c gets blocks c & c+256 =
// same bh, complementary tiles (const 34 iters/CU), 16 waves/CU.
__global__ __launch_bounds__(512, 2) void attn_fwd(
    const bf16_t* __restrict__ q,    // [B,H,S,DK], pre-scaled by Q_SCALE
    const bf16_t* __restrict__ k,    // [B,H,S,DK]
    const bf16_t* __restrict__ vt,   // [B,H,DK,S]
    bf16_t* __restrict__ ao) {       // [B*S, H*DK]
  const int blk = blockIdx.x;                      // 0..511
  const int half = blk >> 8;
  const int low = blk & 255;
  const int bh = (low & 7) * 4 + ((low >> 3) & 3); // XCD-local head mapping
  const int qp = low >> 5;                         // 0..7
  const int qt = half ? (15 - qp) : qp;            // 0..15 (128-row tiles)
  const int tid = threadIdx.x;
  const int lane = tid & 63, w = tid >> 6;
  const int cl = lane & 15, hl = lane >> 4;
  const bf16_t* qb = q + (size_t)bh * S_LEN * D_HEAD;
  const bf16_t* kb = k + (size_t)bh * S_LEN * D_HEAD;
  const bf16_t* vb = vt + (size_t)bh * D_HEAD * S_LEN;
  const int b = bh >> 4, h = bh & 15;

  // K/V double buffer: [buf][K=0/V=1][64 rows x 64 elems] bf16 (32 KB)
  // P tiles: per-wave [16 rows][72] bf16 (18 KB). Total 50 KB.
  __shared__ bf16_t kvbuf[2][2][4096];
  __shared__ bf16_t plds[8][16][72];

  const int srow = tid >> 3;               // 0..63
  const int scc = (tid & 7) ^ (srow & 7);  // swizzled 8-elem chunk index
  const int sw = cl & 7;                   // read-side swizzle key

  const int row0 = qt * 128 + w * 16;
  const int ktb = 2 * qt + 1;              // last K-tile index

  // Q fragments (B-operand): lane (cl,hl) holds Q[row0+cl][hl*8+e]
  const bf16_t* qr = qb + (size_t)(row0 + cl) * D_HEAD + hl * 8;
  bf16x8 qf0 = *reinterpret_cast<const bf16x8*>(qr);
  bf16x8 qf1 = *reinterpret_cast<const bf16x8*>(qr + 32);

  float mrow = -1e30f, lrow = 0.f;
  f32x4 acco[4];
  #pragma unroll
  for (int db = 0; db < 4; ++db) acco[db] = (f32x4){0.f, 0.f, 0.f, 0.f};

  // prologue: stage kt=0 into buf 0
  gload_lds16(kb + (size_t)srow * D_HEAD + scc * 8, &kvbuf[0][0][w << 9]);
  gload_lds16(vb + (size_t)srow * S_LEN + scc * 8,  &kvbuf[0][1][w << 9]);
  __syncthreads();

  int cur = 0;
  for (int kt = 0; kt <= ktb; ++kt) {
    // stage next K/V tile into the other buffer (latency hides under compute)
    if (kt < ktb) {
      gload_lds16(kb + (size_t)((kt + 1) * 64 + srow) * D_HEAD + scc * 8,
                  &kvbuf[cur ^ 1][0][w << 9]);
      gload_lds16(vb + (size_t)srow * S_LEN + (kt + 1) * 64 + scc * 8,
                  &kvbuf[cur ^ 1][1][w << 9]);
    }

    const bool act = (kt * 64) <= (row0 + 15);
    if (act) {
      const bf16_t* kB = kvbuf[cur][0];
      const bf16_t* vB = kvbuf[cur][1];
      // K fragments (A-operand): K[kt*64+nb*16+cl][hl*8+e], swizzled read
      bf16x8 kf[4][2], vf[4][2];
      #pragma unroll
      for (int nb = 0; nb < 4; ++nb) {
        const bf16_t* kr = kB + (nb * 16 + cl) * 64;
        kf[nb][0] = *reinterpret_cast<const bf16x8*>(kr + ((hl ^ sw) << 3));
        kf[nb][1] = *reinterpret_cast<const bf16x8*>(kr + (((hl + 4) ^ sw) << 3));
      }
      #pragma unroll
      for (int db = 0; db < 4; ++db) {
        const bf16_t* vr = vB + (db * 16 + cl) * 64;
        vf[db][0] = *reinterpret_cast<const bf16x8*>(vr + ((hl ^ sw) << 3));
        vf[db][1] = *reinterpret_cast<const bf16x8*>(vr + (((hl + 4) ^ sw) << 3));
      }

      // QK^T swapped: sacc[nb][jj] = S[qrow=row0+cl][kpos=kt*64+nb*16+hl*4+jj]
      f32x4 sacc[4];
      __builtin_amdgcn_s_setprio(1);
      #pragma unroll
      for (int nb = 0; nb < 4; ++nb) {
        f32x4 s = (f32x4){0.f, 0.f, 0.f, 0.f};
        s = __builtin_amdgcn_mfma_f32_16x16x32_bf16(kf[nb][0], qf0, s, 0, 0, 0);
        s = __builtin_amdgcn_mfma_f32_16x16x32_bf16(kf[nb][1], qf1, s, 0, 0, 0);
        sacc[nb] = s;
      }
      __builtin_amdgcn_s_setprio(0);

      // softmax: per-lane row state, in-lane reductions + 2 shfl
      const int qrow = row0 + cl;
      if (kt * 64 + 63 > qrow) {  // diagonal overlap: causal mask
        #pragma unroll
        for (int nb = 0; nb < 4; ++nb)
          #pragma unroll
          for (int jj = 0; jj < 4; ++jj) {
            int kpos = kt * 64 + nb * 16 + hl * 4 + jj;
            if (kpos > qrow) sacc[nb][jj] = -1e30f;
          }
      }
      float tm = sacc[0][0];
      #pragma unroll
      for (int nb = 0; nb < 4; ++nb)
        #pragma unroll
        for (int jj = 0; jj < 4; ++jj)
          tm = fmaxf(tm, sacc[nb][jj]);
      tm = fmaxf(tm, __shfl_xor(tm, 16));
      tm = fmaxf(tm, __shfl_xor(tm, 32));
      // defer-max (T13, THR=8)
      if (__any(tm > mrow + 8.f)) {
        float mnew = fmaxf(mrow, tm);
        float corr = __builtin_amdgcn_exp2f(mrow - mnew);
        mrow = mnew;
        lrow *= corr;
        #pragma unroll
        for (int db = 0; db < 4; ++db) acco[db] *= corr;
      }
      float rs = 0.f;
      #pragma unroll
      for (int nb = 0; nb < 4; ++nb)
        #pragma unroll
        for (int jj = 0; jj < 4; ++jj) {
          float p = __builtin_amdgcn_exp2f(sacc[nb][jj] - mrow);
          sacc[nb][jj] = p;
          rs += p;
        }
      rs += __shfl_xor(rs, 16);
      rs += __shfl_xor(rs, 32);
      lrow += rs;
      // P -> LDS: row=cl (qrow), col=kpos local; cvt_pk pairs -> one b64/nb
      #pragma unroll
      for (int nb = 0; nb < 4; ++nb) {
        uint2 u;
        u.x = cvt_pk_bf16(sacc[nb][0], sacc[nb][1]);
        u.y = cvt_pk_bf16(sacc[nb][2], sacc[nb][3]);
        *reinterpret_cast<uint2*>(&plds[w][cl][nb * 16 + hl * 4]) = u;
      }

      // PV swapped: acco = mfma(V^T, P): D[d=db*16+hl*4+j][qrow=cl]
      bf16x8 pf0 = *reinterpret_cast<const bf16x8*>(&plds[w][cl][hl * 8]);
      bf16x8 pf1 = *reinterpret_cast<const bf16x8*>(&plds[w][cl][32 + hl * 8]);
      __builtin_amdgcn_s_setprio(1);
      #pragma unroll
      for (int db = 0; db < 4; ++db) {
        acco[db] = __builtin_amdgcn_mfma_f32_16x16x32_bf16(vf[db][0], pf0, acco[db], 0, 0, 0);
        acco[db] = __builtin_amdgcn_mfma_f32_16x16x32_bf16(vf[db][1], pf1, acco[db], 0, 0, 0);
      }
      __builtin_amdgcn_s_setprio(0);
    }

    __syncthreads();   // next buffer staged (vmcnt drained) + buf[cur] reads done
    cur ^= 1;
  }

  // output: O[qrow][d] / lrow
  {
    float linv = 1.f / lrow;
    const int qrow = row0 + cl;
    #pragma unroll
    for (int db = 0; db < 4; ++db) {
      uint2 u;
      u.x = cvt_pk_bf16(acco[db][0] * linv, acco[db][1] * linv);
      u.y = cvt_pk_bf16(acco[db][2] * linv, acco[db][3] * linv);
      *reinterpret_cast<uint2*>(
          ao + ((size_t)(b * S_LEN) + qrow) * D_MODEL + h * D_HEAD + db * 16 + hl * 4) = u;
    }
  }
}

// ---------------------------------------------------------------------------
extern "C" void kernel_launch(void* const* d_in, const int* in_sizes, int n_in,
                              void* d_out, int out_size, void* d_ws, size_t ws_size,
                              hipStream_t stream) {
  const float* x      = (const float*)d_in[0];
  const float* attn_w = (const float*)d_in[1];
  const float* attn_b = (const float*)d_in[2];
  const float* proj_w = (const float*)d_in[3];
  const float* proj_b = (const float*)d_in[4];
  float* out = (float*)d_out;
  char* ws = (char*)d_ws;

  bf16_t* xb  = (bf16_t*)(ws + OFF_XB);
  bf16_t* wb  = (bf16_t*)(ws + OFF_WB);
  bf16_t* pwb = (bf16_t*)(ws + OFF_PWB);
  bf16_t* qb  = (bf16_t*)(ws + OFF_Q);
  bf16_t* kb  = (bf16_t*)(ws + OFF_K);
  bf16_t* vtb = (bf16_t*)(ws + OFF_VT);
  bf16_t* aob = (bf16_t*)(ws + OFF_AO);

  const int n4a = M_ROWS * D_MODEL / 4;
  const int n4b = QKV_N * D_MODEL / 4;
  const int n4c = D_MODEL * D_MODEL / 4;
  const int n4 = n4a + n4b + n4c;
  cvt3_f32_bf16<<<(n4 + 255) / 256, 256, 0, stream>>>(x, xb, n4a, attn_w, wb, n4b,
                                                      proj_w, pwb, n4c);

  gemm_qkv<<<dim3(768), 256, 0, stream>>>(
      xb, wb, attn_b, qb, kb, vtb, M_ROWS, QKV_N, D_MODEL);

  attn_fwd<<<dim3(512), 512, 0, stream>>>(qb, kb, vtb, aob);

  gemm_proj64<<<dim3(512), 256, 0, stream>>>(aob, pwb, proj_b, out,
                                             M_ROWS, D_MODEL, D_MODEL);
}

// Round 36
// 111.760 us; speedup vs baseline: 1.0033x; 1.0033x over previous
//
#include <hip/hip_runtime.h>
#include <hip/hip_bf16.h>
#include <stdint.h>

// ---------------------------------------------------------------------------
// OptimizedMultiHeadAttn: x:[2,2048,1024] f32, attn_w:[3072,1024], attn_b:[3072],
// proj_w:[1024,1024], proj_b:[1024]  ->  out:[2,2048,1024] f32
// Pipeline: cvt3 -> QKV gemm_bt (scatter Q/K/V^T) -> flash attn -> proj gemm64
//
// FINAL (verified 111.79-112.42us over eight runs): cvt3 (near HBM roofline)
// -> gemm_qkv 128^2 (256,3), XCD-compact map, coalesced epilogues -> attn
// (46.9us: swapped QK/PV, exp2 softmax, defer-max, LDS-staged K/V dbuf,
// split-block paired causal schedule, 16 waves/CU) -> gemm_proj64 64x128,
// 512 blocks = 2/CU. Session: 304.7us baseline -> 111.8us, 2.73x.
// ---------------------------------------------------------------------------

typedef __bf16 bf16_t;
typedef __bf16 bf16x8 __attribute__((ext_vector_type(8)));
typedef float f32x4 __attribute__((ext_vector_type(4)));

#define B_SZ 2
#define S_LEN 2048
#define D_MODEL 1024
#define N_HEADS 16
#define D_HEAD 64
#define M_ROWS (B_SZ * S_LEN)          // 4096
#define QKV_N (3 * N_HEADS * D_HEAD)   // 3072

// Q pre-scale: 1/sqrt(64) * log2(e)  (softmax runs in exp2 domain)
#define Q_SCALE 0.1803368801111204f

// workspace layout (bytes); total 48 MiB
#define OFF_XB  (0ull)
#define OFF_WB  (8ull  << 20)
#define OFF_PWB (14ull << 20)
#define OFF_Q   (16ull << 20)
#define OFF_K   (24ull << 20)
#define OFF_VT  (32ull << 20)
#define OFF_AO  (40ull << 20)

__device__ __forceinline__ unsigned short f2bf_u(float f) {
  union { float f; unsigned u; } v; v.f = f;
  unsigned r = v.u + 0x7fffu + ((v.u >> 16) & 1u);  // RNE
  return (unsigned short)(r >> 16);
}
__device__ __forceinline__ bf16_t f2bf(float f) {
  unsigned short u = f2bf_u(f);
  return __builtin_bit_cast(bf16_t, u);
}
// v_cvt_pk_bf16_f32: D[15:0]=bf16(lo), D[31:16]=bf16(hi) (RNE). No builtin.
__device__ __forceinline__ unsigned cvt_pk_bf16(float lo, float hi) {
  unsigned r;
  asm volatile("v_cvt_pk_bf16_f32 %0, %1, %2" : "=v"(r) : "v"(lo), "v"(hi));
  return r;
}

// ---------------------------------------------------------------------------
__global__ void cvt3_f32_bf16(const float* __restrict__ sa, bf16_t* __restrict__ da, int n4a,
                              const float* __restrict__ sb, bf16_t* __restrict__ db, int n4b,
                              const float* __restrict__ sc, bf16_t* __restrict__ dc, int n4c) {
  int i = blockIdx.x * blockDim.x + threadIdx.x;
  const float* s; bf16_t* d; int j = i;
  if (i < n4a) { s = sa; d = da; }
  else if ((j = i - n4a) < n4b) { s = sb; d = db; }
  else if ((j = i - n4a - n4b) < n4c) { s = sc; d = dc; }
  else return;
  float4 f = reinterpret_cast<const float4*>(s)[j];
  ushort4 o;
  o.x = f2bf_u(f.x); o.y = f2bf_u(f.y); o.z = f2bf_u(f.z); o.w = f2bf_u(f.w);
  reinterpret_cast<ushort4*>(d)[j] = o;
}

// ---------------------------------------------------------------------------
// gemm_qkv: C = A * Bt^T + bias, 128x128 tile, BK=64, 4 waves.
// Single-buffer 2-barrier K-loop (m97 structure), (256,3), XCD-compact remap.
// Coalesced epilogues (verified R23).
#define BM 128
#define BN 128
#define BK 64

__device__ __forceinline__ void gload_lds16(const bf16_t* g, bf16_t* l) {
  __builtin_amdgcn_global_load_lds((__attribute__((address_space(1))) void*)g,
                                   (__attribute__((address_space(3))) void*)l,
                                   16, 0, 0);
}

__device__ __forceinline__ bf16x8 lds_frag(const bf16_t* lds, int row, int kchunk) {
  int pos = kchunk ^ (row & 7);
  return *reinterpret_cast<const bf16x8*>(lds + row * BK + pos * 8);
}

__global__ __launch_bounds__(256, 3) void gemm_qkv(
    const bf16_t* __restrict__ A, const bf16_t* __restrict__ Bt,
    const float* __restrict__ bias,
    bf16_t* __restrict__ qout, bf16_t* __restrict__ kout,
    bf16_t* __restrict__ vtout,
    int M, int N, int K) {
  // union LDS: K-loop uses As(16KB)+Bs(16KB); epilogue reuses as C-tile
  // (bf16 [128][136] = 34816B).
  __shared__ __align__(16) char smem[34816];
  bf16_t* As = reinterpret_cast<bf16_t*>(smem);
  bf16_t* Bs = As + BM * BK;

  const int tid = threadIdx.x;
  const int lane = tid & 63;
  const int wid = tid >> 6;
  const int wr = wid >> 1, wc = wid & 1;
  const int cl = lane & 15, hl = lane >> 4;

  // XCD-compact tile mapping (bijective): 768 blocks, 32m x 24n tiles
  const int id = blockIdx.x;
  const int xcd = id & 7, loc = id >> 3;
  const int mtile = (xcd & 3) * 8 + (loc & 7);
  const int ntile = (xcd >> 2) * 12 + (loc >> 3);
  const int m0 = mtile * BM, n0 = ntile * BN;

  f32x4 acc[4][4];
  #pragma unroll
  for (int m = 0; m < 4; ++m)
    #pragma unroll
    for (int n = 0; n < 4; ++n)
      acc[m][n] = (f32x4){0.f, 0.f, 0.f, 0.f};

  for (int kt = 0; kt < K; kt += BK) {
    #pragma unroll
    for (int it = 0; it < 4; ++it) {
      int chunk = it * 256 + tid;
      int row = chunk >> 3, cpos = chunk & 7;
      int csrc = cpos ^ (row & 7);
      bf16_t* ldsA = As + (it * 256 + wid * 64) * 8;
      bf16_t* ldsB = Bs + (it * 256 + wid * 64) * 8;
      gload_lds16(A  + (size_t)(m0 + row) * K + kt + csrc * 8, ldsA);
      gload_lds16(Bt + (size_t)(n0 + row) * K + kt + csrc * 8, ldsB);
    }
    __syncthreads();

    bf16x8 af[2][4], bfr[2][4];
    #pragma unroll
    for (int kk = 0; kk < 2; ++kk) {
      #pragma unroll
      for (int m = 0; m < 4; ++m)
        af[kk][m] = lds_frag(As, wr * 64 + m * 16 + cl, kk * 4 + hl);
      #pragma unroll
      for (int n = 0; n < 4; ++n)
        bfr[kk][n] = lds_frag(Bs, wc * 64 + n * 16 + cl, kk * 4 + hl);
    }
    __builtin_amdgcn_s_setprio(1);
    #pragma unroll
    for (int m = 0; m < 4; ++m)
      #pragma unroll
      for (int n = 0; n < 4; ++n) {
        acc[m][n] = __builtin_amdgcn_mfma_f32_16x16x32_bf16(af[0][m], bfr[0][n], acc[m][n], 0, 0, 0);
        acc[m][n] = __builtin_amdgcn_mfma_f32_16x16x32_bf16(af[1][m], bfr[1][n], acc[m][n], 0, 0, 0);
      }
    __builtin_amdgcn_s_setprio(0);
    __syncthreads();   // also guards LDS reuse by the epilogue below
  }

  // epilogue: C/D layout col=lane&15, row=(lane>>4)*4+j (m89-verified)
  const int part = n0 >> 10;         // 0=Q 1=K 2=V (tile never spans parts)
  const int b = m0 >> 11;
  const int sloc = m0 & 2047;        // batch-local s base
  if (part == 2) {
    // V^T: s contiguous in j -> pack and store 8B directly (no LDS)
    #pragma unroll
    for (int n = 0; n < 4; ++n) {
      int ng = n0 + wc * 64 + n * 16 + cl;
      float bv = bias[ng];
      int r = ng & 1023;
      int h = r >> 6, dk = r & 63;
      bf16_t* vrow = vtout + ((size_t)((b * N_HEADS + h) * D_HEAD + dk)) * S_LEN;
      #pragma unroll
      for (int m = 0; m < 4; ++m) {
        int sbase = sloc + wr * 64 + m * 16 + hl * 4;
        uint2 u;
        u.x = cvt_pk_bf16(acc[m][n][0] + bv, acc[m][n][1] + bv);
        u.y = cvt_pk_bf16(acc[m][n][2] + bv, acc[m][n][3] + bv);
        *reinterpret_cast<uint2*>(vrow + sbase) = u;
      }
    }
  } else {
    // Q/K: LDS transpose -> coalesced 128B row-segment stores
    const float scale = (part == 0) ? Q_SCALE : 1.0f;
    bf16_t (*ct)[136] = reinterpret_cast<bf16_t(*)[136]>(smem);
    #pragma unroll
    for (int n = 0; n < 4; ++n) {
      int colb = wc * 64 + n * 16 + cl;
      float bv = bias[n0 + colb];
      #pragma unroll
      for (int m = 0; m < 4; ++m)
        #pragma unroll
        for (int j = 0; j < 4; ++j) {
          int row = wr * 64 + m * 16 + hl * 4 + j;
          ct[row][colb] = f2bf((acc[m][n][j] + bv) * scale);
        }
    }
    __syncthreads();
    bf16_t* dst = (part == 0) ? qout : kout;
    const int row = tid >> 1, seg = tid & 1;
    const int ngs = n0 + seg * 64;
    const int h = (ngs & 1023) >> 6;
    const int s = sloc + row;          // batch-local
    bf16_t* drow = dst + ((size_t)((b * N_HEADS + h) * S_LEN + s)) * D_HEAD;
    #pragma unroll
    for (int kk = 0; kk < 8; ++kk) {   // 8 x 16B = full 64-elem dk segment
      uint4 v = *reinterpret_cast<const uint4*>(&ct[row][seg * 64 + kk * 8]);
      *reinterpret_cast<uint4*>(drow + kk * 8) = v;
    }
  }
}

// ---------------------------------------------------------------------------
// gemm_proj64: C[4096,1024] = A[4096,1024]*Bt[1024,1024]^T + bias (f32 out).
// 64x128 tile, BK=64, 4 waves (wave wid owns cols wid*32..+31: acc[4][2]).
// Grid 64m x 8n = 512 blocks = 2 blocks/CU (R30 occupancy fix). Same staging
// scheme; 2-pass f32 LDS-transpose epilogue. XCD-compact bijective map.
__global__ __launch_bounds__(256, 3) void gemm_proj64(
    const bf16_t* __restrict__ A, const bf16_t* __restrict__ Bt,
    const float* __restrict__ bias, float* __restrict__ fout,
    int M, int N, int K) {
  // LDS: K-loop As(8KB)+Bs(16KB)=24KB; epilogue f32 [64][68]=17408B.
  __shared__ __align__(16) char smem[34816];
  bf16_t* As = reinterpret_cast<bf16_t*>(smem);   // [64][64]
  bf16_t* Bs = As + 64 * 64;                      // [128][64]

  const int tid = threadIdx.x;
  const int lane = tid & 63;
  const int wid = tid >> 6;                       // 0..3 (column wave)
  const int cl = lane & 15, hl = lane >> 4;

  const int id = blockIdx.x;                      // 0..511
  const int xcd = id & 7, loc = id >> 3;          // loc 0..63
  const int mtile = xcd * 8 + (loc & 7);          // 0..63
  const int ntile = loc >> 3;                     // 0..7
  const int m0 = mtile * 64, n0 = ntile * 128;

  f32x4 acc[4][2];
  #pragma unroll
  for (int m = 0; m < 4; ++m)
    #pragma unroll
    for (int n = 0; n < 2; ++n)
      acc[m][n] = (f32x4){0.f, 0.f, 0.f, 0.f};

  for (int kt = 0; kt < K; kt += BK) {
    #pragma unroll
    for (int it = 0; it < 2; ++it) {
      int c = it * 256 + tid;
      int row = c >> 3, cpos = c & 7;
      int csrc = cpos ^ (row & 7);
      gload_lds16(A + (size_t)(m0 + row) * K + kt + csrc * 8,
                  As + (it * 256 + wid * 64) * 8);
    }
    #pragma unroll
    for (int it = 0; it < 4; ++it) {
      int c = it * 256 + tid;
      int row = c >> 3, cpos = c & 7;
      int csrc = cpos ^ (row & 7);
      gload_lds16(Bt + (size_t)(n0 + row) * K + kt + csrc * 8,
                  Bs + (it * 256 + wid * 64) * 8);
    }
    __syncthreads();

    bf16x8 af[2][4], bfr[2][2];
    #pragma unroll
    for (int kk = 0; kk < 2; ++kk) {
      #pragma unroll
      for (int m = 0; m < 4; ++m)
        af[kk][m] = lds_frag(As, m * 16 + cl, kk * 4 + hl);
      #pragma unroll
      for (int n = 0; n < 2; ++n)
        bfr[kk][n] = lds_frag(Bs, wid * 32 + n * 16 + cl, kk * 4 + hl);
    }
    __builtin_amdgcn_s_setprio(1);
    #pragma unroll
    for (int m = 0; m < 4; ++m)
      #pragma unroll
      for (int n = 0; n < 2; ++n) {
        acc[m][n] = __builtin_amdgcn_mfma_f32_16x16x32_bf16(af[0][m], bfr[0][n], acc[m][n], 0, 0, 0);
        acc[m][n] = __builtin_amdgcn_mfma_f32_16x16x32_bf16(af[1][m], bfr[1][n], acc[m][n], 0, 0, 0);
      }
    __builtin_amdgcn_s_setprio(0);
    __syncthreads();   // also guards LDS reuse by the epilogue below
  }

  // epilogue: f32 LDS transpose in two 64-col passes -> float4 stores.
  float (*ctf)[68] = reinterpret_cast<float(*)[68]>(smem);
  #pragma unroll 1
  for (int p = 0; p < 2; ++p) {
    if ((wid >> 1) == p) {
      const int colh = (wid & 1) * 32;
      #pragma unroll
      for (int n = 0; n < 2; ++n) {
        int coll = colh + n * 16 + cl;            // 0..63 within the pass
        float bv = bias[n0 + p * 64 + coll];
        #pragma unroll
        for (int m = 0; m < 4; ++m)
          #pragma unroll
          for (int j = 0; j < 4; ++j)
            ctf[m * 16 + hl * 4 + j][coll] = acc[m][n][j] + bv;
      }
    }
    __syncthreads();
    {
      const int row = tid >> 2, sub = tid & 3;    // 16 f32 (64B) per thread
      float* drow = fout + (size_t)(m0 + row) * N + n0 + p * 64 + sub * 16;
      #pragma unroll
      for (int kk = 0; kk < 4; ++kk) {
        float4 v = *reinterpret_cast<const float4*>(&ctf[row][sub * 16 + kk * 4]);
        *reinterpret_cast<float4*>(drow + kk * 4) = v;
      }
    }
    __syncthreads();
  }
}

// ---------------------------------------------------------------------------
// Flash attention (R18/R23 version — 46.9us measured).
// Causal, exp2 domain, swapped-operand, LDS-staged K/V; paired tiles split
// across two blocks: grid 512, half=blk>>8; CU c gets blocks c & c+256 =
// same bh, complementary tiles (const 34 iters/CU), 16 waves/CU.
__global__ __launch_bounds__(512, 2) void attn_fwd(
    const bf16_t* __restrict__ q,    // [B,H,S,DK], pre-scaled by Q_SCALE
    const bf16_t* __restrict__ k,    // [B,H,S,DK]
    const bf16_t* __restrict__ vt,   // [B,H,DK,S]
    bf16_t* __restrict__ ao) {       // [B*S, H*DK]
  const int blk = blockIdx.x;                      // 0..511
  const int half = blk >> 8;
  const int low = blk & 255;
  const int bh = (low & 7) * 4 + ((low >> 3) & 3); // XCD-local head mapping
  const int qp = low >> 5;                         // 0..7
  const int qt = half ? (15 - qp) : qp;            // 0..15 (128-row tiles)
  const int tid = threadIdx.x;
  const int lane = tid & 63, w = tid >> 6;
  const int cl = lane & 15, hl = lane >> 4;
  const bf16_t* qb = q + (size_t)bh * S_LEN * D_HEAD;
  const bf16_t* kb = k + (size_t)bh * S_LEN * D_HEAD;
  const bf16_t* vb = vt + (size_t)bh * D_HEAD * S_LEN;
  const int b = bh >> 4, h = bh & 15;

  // K/V double buffer: [buf][K=0/V=1][64 rows x 64 elems] bf16 (32 KB)
  // P tiles: per-wave [16 rows][72] bf16 (18 KB). Total 50 KB.
  __shared__ bf16_t kvbuf[2][2][4096];
  __shared__ bf16_t plds[8][16][72];

  const int srow = tid >> 3;               // 0..63
  const int scc = (tid & 7) ^ (srow & 7);  // swizzled 8-elem chunk index
  const int sw = cl & 7;                   // read-side swizzle key

  const int row0 = qt * 128 + w * 16;
  const int ktb = 2 * qt + 1;              // last K-tile index

  // Q fragments (B-operand): lane (cl,hl) holds Q[row0+cl][hl*8+e]
  const bf16_t* qr = qb + (size_t)(row0 + cl) * D_HEAD + hl * 8;
  bf16x8 qf0 = *reinterpret_cast<const bf16x8*>(qr);
  bf16x8 qf1 = *reinterpret_cast<const bf16x8*>(qr + 32);

  float mrow = -1e30f, lrow = 0.f;
  f32x4 acco[4];
  #pragma unroll
  for (int db = 0; db < 4; ++db) acco[db] = (f32x4){0.f, 0.f, 0.f, 0.f};

  // prologue: stage kt=0 into buf 0
  gload_lds16(kb + (size_t)srow * D_HEAD + scc * 8, &kvbuf[0][0][w << 9]);
  gload_lds16(vb + (size_t)srow * S_LEN + scc * 8,  &kvbuf[0][1][w << 9]);
  __syncthreads();

  int cur = 0;
  for (int kt = 0; kt <= ktb; ++kt) {
    // stage next K/V tile into the other buffer (latency hides under compute)
    if (kt < ktb) {
      gload_lds16(kb + (size_t)((kt + 1) * 64 + srow) * D_HEAD + scc * 8,
                  &kvbuf[cur ^ 1][0][w << 9]);
      gload_lds16(vb + (size_t)srow * S_LEN + (kt + 1) * 64 + scc * 8,
                  &kvbuf[cur ^ 1][1][w << 9]);
    }

    const bool act = (kt * 64) <= (row0 + 15);
    if (act) {
      const bf16_t* kB = kvbuf[cur][0];
      const bf16_t* vB = kvbuf[cur][1];
      // K fragments (A-operand): K[kt*64+nb*16+cl][hl*8+e], swizzled read
      bf16x8 kf[4][2], vf[4][2];
      #pragma unroll
      for (int nb = 0; nb < 4; ++nb) {
        const bf16_t* kr = kB + (nb * 16 + cl) * 64;
        kf[nb][0] = *reinterpret_cast<const bf16x8*>(kr + ((hl ^ sw) << 3));
        kf[nb][1] = *reinterpret_cast<const bf16x8*>(kr + (((hl + 4) ^ sw) << 3));
      }
      #pragma unroll
      for (int db = 0; db < 4; ++db) {
        const bf16_t* vr = vB + (db * 16 + cl) * 64;
        vf[db][0] = *reinterpret_cast<const bf16x8*>(vr + ((hl ^ sw) << 3));
        vf[db][1] = *reinterpret_cast<const bf16x8*>(vr + (((hl + 4) ^ sw) << 3));
      }

      // QK^T swapped: sacc[nb][jj] = S[qrow=row0+cl][kpos=kt*64+nb*16+hl*4+jj]
      f32x4 sacc[4];
      __builtin_amdgcn_s_setprio(1);
      #pragma unroll
      for (int nb = 0; nb < 4; ++nb) {
        f32x4 s = (f32x4){0.f, 0.f, 0.f, 0.f};
        s = __builtin_amdgcn_mfma_f32_16x16x32_bf16(kf[nb][0], qf0, s, 0, 0, 0);
        s = __builtin_amdgcn_mfma_f32_16x16x32_bf16(kf[nb][1], qf1, s, 0, 0, 0);
        sacc[nb] = s;
      }
      __builtin_amdgcn_s_setprio(0);

      // softmax: per-lane row state, in-lane reductions + 2 shfl
      const int qrow = row0 + cl;
      if (kt * 64 + 63 > qrow) {  // diagonal overlap: causal mask
        #pragma unroll
        for (int nb = 0; nb < 4; ++nb)
          #pragma unroll
          for (int jj = 0; jj < 4; ++jj) {
            int kpos = kt * 64 + nb * 16 + hl * 4 + jj;
            if (kpos > qrow) sacc[nb][jj] = -1e30f;
          }
      }
      float tm = sacc[0][0];
      #pragma unroll
      for (int nb = 0; nb < 4; ++nb)
        #pragma unroll
        for (int jj = 0; jj < 4; ++jj)
          tm = fmaxf(tm, sacc[nb][jj]);
      tm = fmaxf(tm, __shfl_xor(tm, 16));
      tm = fmaxf(tm, __shfl_xor(tm, 32));
      // defer-max (T13, THR=8)
      if (__any(tm > mrow + 8.f)) {
        float mnew = fmaxf(mrow, tm);
        float corr = __builtin_amdgcn_exp2f(mrow - mnew);
        mrow = mnew;
        lrow *= corr;
        #pragma unroll
        for (int db = 0; db < 4; ++db) acco[db] *= corr;
      }
      float rs = 0.f;
      #pragma unroll
      for (int nb = 0; nb < 4; ++nb)
        #pragma unroll
        for (int jj = 0; jj < 4; ++jj) {
          float p = __builtin_amdgcn_exp2f(sacc[nb][jj] - mrow);
          sacc[nb][jj] = p;
          rs += p;
        }
      rs += __shfl_xor(rs, 16);
      rs += __shfl_xor(rs, 32);
      lrow += rs;
      // P -> LDS: row=cl (qrow), col=kpos local; cvt_pk pairs -> one b64/nb
      #pragma unroll
      for (int nb = 0; nb < 4; ++nb) {
        uint2 u;
        u.x = cvt_pk_bf16(sacc[nb][0], sacc[nb][1]);
        u.y = cvt_pk_bf16(sacc[nb][2], sacc[nb][3]);
        *reinterpret_cast<uint2*>(&plds[w][cl][nb * 16 + hl * 4]) = u;
      }

      // PV swapped: acco = mfma(V^T, P): D[d=db*16+hl*4+j][qrow=cl]
      bf16x8 pf0 = *reinterpret_cast<const bf16x8*>(&plds[w][cl][hl * 8]);
      bf16x8 pf1 = *reinterpret_cast<const bf16x8*>(&plds[w][cl][32 + hl * 8]);
      __builtin_amdgcn_s_setprio(1);
      #pragma unroll
      for (int db = 0; db < 4; ++db) {
        acco[db] = __builtin_amdgcn_mfma_f32_16x16x32_bf16(vf[db][0], pf0, acco[db], 0, 0, 0);
        acco[db] = __builtin_amdgcn_mfma_f32_16x16x32_bf16(vf[db][1], pf1, acco[db], 0, 0, 0);
      }
      __builtin_amdgcn_s_setprio(0);
    }

    __syncthreads();   // next buffer staged (vmcnt drained) + buf[cur] reads done
    cur ^= 1;
  }

  // output: O[qrow][d] / lrow
  {
    float linv = 1.f / lrow;
    const int qrow = row0 + cl;
    #pragma unroll
    for (int db = 0; db < 4; ++db) {
      uint2 u;
      u.x = cvt_pk_bf16(acco[db][0] * linv, acco[db][1] * linv);
      u.y = cvt_pk_bf16(acco[db][2] * linv, acco[db][3] * linv);
      *reinterpret_cast<uint2*>(
          ao + ((size_t)(b * S_LEN) + qrow) * D_MODEL + h * D_HEAD + db * 16 + hl * 4) = u;
    }
  }
}

// ---------------------------------------------------------------------------
extern "C" void kernel_launch(void* const* d_in, const int* in_sizes, int n_in,
                              void* d_out, int out_size, void* d_ws, size_t ws_size,
                              hipStream_t stream) {
  const float* x      = (const float*)d_in[0];
  const float* attn_w = (const float*)d_in[1];
  const float* attn_b = (const float*)d_in[2];
  const float* proj_w = (const float*)d_in[3];
  const float* proj_b = (const float*)d_in[4];
  float* out = (float*)d_out;
  char* ws = (char*)d_ws;

  bf16_t* xb  = (bf16_t*)(ws + OFF_XB);
  bf16_t* wb  = (bf16_t*)(ws + OFF_WB);
  bf16_t* pwb = (bf16_t*)(ws + OFF_PWB);
  bf16_t* qb  = (bf16_t*)(ws + OFF_Q);
  bf16_t* kb  = (bf16_t*)(ws + OFF_K);
  bf16_t* vtb = (bf16_t*)(ws + OFF_VT);
  bf16_t* aob = (bf16_t*)(ws + OFF_AO);

  const int n4a = M_ROWS * D_MODEL / 4;
  const int n4b = QKV_N * D_MODEL / 4;
  const int n4c = D_MODEL * D_MODEL / 4;
  const int n4 = n4a + n4b + n4c;
  cvt3_f32_bf16<<<(n4 + 255) / 256, 256, 0, stream>>>(x, xb, n4a, attn_w, wb, n4b,
                                                      proj_w, pwb, n4c);

  gemm_qkv<<<dim3(768), 256, 0, stream>>>(
      xb, wb, attn_b, qb, kb, vtb, M_ROWS, QKV_N, D_MODEL);

  attn_fwd<<<dim3(512), 512, 0, stream>>>(qb, kb, vtb, aob);

  gemm_proj64<<<dim3(512), 256, 0, stream>>>(aob, pwb, proj_b, out,
                                             M_ROWS, D_MODEL, D_MODEL);
}